// Round 6
// baseline (1532.625 us; speedup 1.0000x reference)
//
#include <hip/hip_runtime.h>
#include <hip/hip_bf16.h>
#include <math.h>

// ---------------------------------------------------------------------------
// R6: conv3m — oc-split (512 blocks, 2/CU), acc[2][8] (64 VGPR), tile XOR
//     swizzle. k_step5 — barrier-free K-loop: A(x|h) LDS-resident (staged
//     once), B weights direct from L2; block = 32 batch x 128 gate-cols.
// ---------------------------------------------------------------------------

namespace {

constexpr int S_ = 32, B_ = 128, H_ = 1024, P_ = 196, OC_ = 128;
constexpr int NE = B_ * OC_ * P_;        // elems of a [B][128][196] slab
constexpr int KX = 384;                  // padded x-K (300 -> 384)

typedef __attribute__((ext_vector_type(8))) short short8v;
typedef __attribute__((ext_vector_type(4))) float f32x4;
#define MFMA16(a, b, c) __builtin_amdgcn_mfma_f32_16x16x32_bf16((a), (b), (c), 0, 0, 0)

__device__ __forceinline__ float sigm(float x){ return 1.0f/(1.0f + expf(-x)); }
__device__ __forceinline__ float c0f(int p){ return ((float)p/14.0f - 7.0f)/7.0f; }
__device__ __forceinline__ float c1f(int p){ return ((float)(p%14) - 7.0f)/7.0f; }
__device__ __forceinline__ unsigned short f2bf(float x){
  __hip_bfloat16 h = __float2bfloat16(x);
  return *reinterpret_cast<unsigned short*>(&h);
}

// ---------------- weight convert f32 -> bf16, K-padded -----------------------
__global__ void k_cvtpad(const float* __restrict__ src, unsigned short* __restrict__ dst,
                         int rows, int ks, int kd){
  int i = blockIdx.x*256 + threadIdx.x;
  if (i >= rows*kd) return;
  int k = i % kd, r = i / kd;
  dst[i] = (k < ks) ? f2bf(src[r*ks + k]) : (unsigned short)0;
}

// conv weights [oc][cin][3][3] f32 -> wT [s][oc][cpad] bf16
__global__ void k_cvt_wT(const float* __restrict__ w, unsigned short* __restrict__ wT,
                         int cin, int cpad){
  int i = blockIdx.x*256 + threadIdx.x;
  if (i >= 9*128*cpad) return;
  int c = i % cpad; int t = i / cpad; int oc = t % 128; int s = t / 128;
  wT[i] = (c < cin) ? f2bf(w[((size_t)oc*cin + c)*9 + s]) : (unsigned short)0;
}

__global__ void k_bias2(const float* __restrict__ bif, const float* __restrict__ bhf,
                        const float* __restrict__ bib, const float* __restrict__ bhb,
                        float* __restrict__ out){
  int i = blockIdx.x*256 + threadIdx.x;
  if (i >= 8192) return;
  out[i] = (i < 4096) ? (bif[i] + bhf[i]) : (bib[i-4096] + bhb[i-4096]);
}

// ---------------- embedding -> bf16 x[s][b][384] ------------------------------
__global__ void k_embed_bf(const int* __restrict__ que, const float* __restrict__ emb,
                           unsigned short* __restrict__ x){
  int idx = blockIdx.x*256 + threadIdx.x;
  if (idx >= S_*B_*KX) return;
  int e = idx % KX; int sb = idx / KX; int b = sb % B_; int s = sb / B_;
  float v = 0.0f;
  if (e < 300){
    int t = que[b*S_ + s];
    if (t != 0) v = emb[t*300 + e];
  }
  x[idx] = f2bf(v);
}

// ---------------- one LSTM step via MFMA (v5: barrier-free K-loop) ------------
// grid (64, 4): x = dir*32 + colslab, y = batch-slab (slow dim -> blocks
// sharing weights are 64 apart = same XCD). block 256 (4 waves).
// Block tile: M = 32 batch rows x N = 128 cols (4 gates x 32 units); wave w
// owns gate w (cols w*32..+32). A (x|h, 32x1408) staged ONCE into LDS;
// B (weights) read directly from L2 inside a barrier-free 44-iter K-loop.
__launch_bounds__(256, 1)
__global__ void k_step5(const unsigned short* __restrict__ xbf,
                        const unsigned short* __restrict__ wihc,
                        const unsigned short* __restrict__ whhc,
                        const float* __restrict__ bias2,
                        const unsigned short* __restrict__ hin,
                        unsigned short* __restrict__ hout,
                        float* __restrict__ cst, float* __restrict__ Q, int s){
  const int dir = blockIdx.x >> 5;
  const int u0  = (blockIdx.x & 31) * 32;
  const int m0g = blockIdx.y * 32;
  const int tid = threadIdx.x, wave = tid >> 6, lane = tid & 63;
  const int lr = lane & 15, lk = lane >> 4;
  const int xs = dir ? (S_-1-s) : s;

  __shared__ unsigned short tA[32][1416];   // [m][k], pad 8
  __shared__ float sG[32][132];

  // ---- stage A once: x rows (384) + h rows (1024), 22 indep loads/thread ----
  {
    const int r = tid >> 3, sg = tid & 7;
    const unsigned short* xr = xbf + ((size_t)xs*B_ + m0g + r)*KX + sg*48;
    #pragma unroll
    for (int q = 0; q < 6; ++q)
      *(short8v*)&tA[r][sg*48 + q*8] = *(const short8v*)(xr + q*8);
    const unsigned short* hr = hin + ((size_t)dir*B_ + m0g + r)*H_ + sg*128;
    #pragma unroll
    for (int q = 0; q < 16; ++q)
      *(short8v*)&tA[r][384 + sg*128 + q*8] = *(const short8v*)(hr + q*8);
  }
  __syncthreads();

  // weight rows for this wave's gate: wrow = gate*1024 + u0 + unit
  const int wr0 = wave*1024 + u0 + lr;
  const unsigned short* bx0 = wihc + (size_t)dir*4096*KX + (size_t)wr0*KX;
  const unsigned short* bx1 = bx0 + (size_t)16*KX;
  const unsigned short* bh0 = whhc + (size_t)dir*4096*H_ + (size_t)wr0*H_;
  const unsigned short* bh1 = bh0 + (size_t)16*H_;

  f32x4 acc00{0,0,0,0}, acc01{0,0,0,0}, acc10{0,0,0,0}, acc11{0,0,0,0};

  // ---- x-part: 12 chunks of K=32 ----
  #pragma unroll
  for (int ch = 0; ch < 12; ++ch){
    const int ko = ch*32 + lk*8;
    short8v a0 = *(short8v*)&tA[lr][ko];
    short8v a1 = *(short8v*)&tA[16 + lr][ko];
    short8v b0 = *(const short8v*)(bx0 + ko);
    short8v b1 = *(const short8v*)(bx1 + ko);
    acc00 = MFMA16(a0, b0, acc00); acc01 = MFMA16(a0, b1, acc01);
    acc10 = MFMA16(a1, b0, acc10); acc11 = MFMA16(a1, b1, acc11);
  }
  // ---- h-part: 32 chunks of K=32 ----
  #pragma unroll
  for (int ch = 0; ch < 32; ++ch){
    const int kb = ch*32 + lk*8;
    const int ka = 384 + kb;
    short8v a0 = *(short8v*)&tA[lr][ka];
    short8v a1 = *(short8v*)&tA[16 + lr][ka];
    short8v b0 = *(const short8v*)(bh0 + kb);
    short8v b1 = *(const short8v*)(bh1 + kb);
    acc00 = MFMA16(a0, b0, acc00); acc01 = MFMA16(a0, b1, acc01);
    acc10 = MFMA16(a1, b0, acc10); acc11 = MFMA16(a1, b1, acc11);
  }

  // ---- recombine: C row = lk*4+j (+16 for mi=1), col = wave*32 + ci*16 + lr --
  #pragma unroll
  for (int j = 0; j < 4; ++j){
    const int rr = lk*4 + j;
    sG[rr][wave*32 + lr]            = acc00[j];
    sG[rr][wave*32 + 16 + lr]       = acc01[j];
    sG[16 + rr][wave*32 + lr]       = acc10[j];
    sG[16 + rr][wave*32 + 16 + lr]  = acc11[j];
  }
  __syncthreads();

  // ---- gate math: 32 m x 32 units, 4 tasks/thread ----
  const float* bb = bias2 + (size_t)dir*4096;
  float* cc = cst + (size_t)dir*B_*H_;
  unsigned short* ho = hout + (size_t)dir*B_*H_;
  #pragma unroll
  for (int t = 0; t < 4; ++t){
    const int idx = tid + t*256;              // 1024 tasks
    const int m = idx >> 5, u = idx & 31;
    const int ug = u0 + u, mg = m0g + m;
    float gi = sG[m][u]      + bb[ug];
    float gf = sG[m][32+u]   + bb[1024+ug];
    float gg = sG[m][64+u]   + bb[2048+ug];
    float go = sG[m][96+u]   + bb[3072+ug];
    float cold = cc[mg*H_ + ug];
    float cn = sigm(gf)*cold + sigm(gi)*tanhf(gg);
    float hn = sigm(go)*tanhf(cn);
    cc[mg*H_ + ug] = cn;
    ho[mg*H_ + ug] = f2bf(hn);
    Q[((size_t)xs*B_ + mg)*2048 + dir*1024 + ug] = hn;
  }
}

// ---------------- qenc L2-normalize (in-place) + enc --------------------------
__global__ void k_qnorm(float* __restrict__ Q, float* __restrict__ enc){
  int sb = blockIdx.x;
  int s = sb >> 7, b = sb & 127;
  float* row = Q + (size_t)sb*2048;
  int tid = threadIdx.x;
  float v[8]; float ss = 0.f;
  #pragma unroll
  for (int i = 0; i < 8; ++i){ v[i] = row[tid*8+i]; ss += v[i]*v[i]; }
  __shared__ float red[256];
  red[tid] = ss; __syncthreads();
  for (int st = 128; st; st >>= 1){
    if (tid < st) red[tid] += red[tid+st];
    __syncthreads();
  }
  float inv = 1.0f / fmaxf(sqrtf(red[0]), 1e-12f);
  #pragma unroll
  for (int i = 0; i < 8; ++i){
    float q = v[i]*inv;
    row[tid*8+i] = q;
    if (s == S_-1) enc[(size_t)b*2048 + tid*8 + i] = q;
  }
}

// ---------------- per-pixel channel sumsq of img ------------------------------
__global__ void k_sqpart(const float* __restrict__ img, float* __restrict__ part){
  int b = blockIdx.x, cq = blockIdx.y;
  int t = threadIdx.x;
  if (t >= P_) return;
  const float* base = img + ((size_t)b*1024 + cq*256)*P_ + t;
  float s = 0.f;
  #pragma unroll 4
  for (int c = 0; c < 256; ++c){ float v = base[c*P_]; s += v*v; }
  part[((size_t)b*4 + cq)*P_ + t] = s;
}

__global__ void k_invnorm(const float* __restrict__ part, float* __restrict__ inv){
  int i = blockIdx.x*256 + threadIdx.x;
  if (i >= B_*P_) return;
  int b = i / P_, p = i % P_;
  float s = part[(b*4+0)*P_+p] + part[(b*4+1)*P_+p]
          + part[(b*4+2)*P_+p] + part[(b*4+3)*P_+p];
  inv[i] = 1.0f / fmaxf(sqrtf(s), 1e-12f);
}

// ---------------- 3x3 conv via MFMA (v4: oc-split + swizzle) ------------------
// grid (128 b, 2 z, 2 ocb); block 256 (4 waves: 2 wfM x 2 wfN).
// Block: M = 64 oc (A = weights from L2), N = 256 padded 16x16 positions
// (B = input tile, LDS dbuf, XOR-swizzled 16B sub-blocks), K chunks of 32.
template<int CIN, int MODE>
__device__ __forceinline__ void conv_stage(unsigned short (*__restrict__ tile)[40],
                                           const float* __restrict__ in,
                                           const float* __restrict__ sInv,
                                           int b, int c0, int tid){
  #pragma unroll
  for (int half = 0; half < 2; ++half){
    const int jn = half ? 12 : 13;
    float r[13];
    #pragma unroll
    for (int j = 0; j < 13; ++j){
      if (j >= jn) break;
      int i = tid + (half*13 + j)*256;
      if (i < 6272){
        int c = i / 196, p = i - c*196;
        int cg = c0 + c;
        float v;
        if (MODE == 0){
          if (cg < 1024)       v = in[((size_t)b*1024 + cg)*P_ + p] * sInv[p];
          else if (cg == 1024) v = c0f(p);
          else if (cg == 1025) v = c1f(p);
          else                 v = 0.f;
        } else {
          v = in[((size_t)b*CIN + cg)*P_ + p];
        }
        r[j] = v;
      }
    }
    #pragma unroll
    for (int j = 0; j < 13; ++j){
      if (j >= jn) break;
      int i = tid + (half*13 + j)*256;
      if (i < 6272){
        int c = i / 196, p = i - c*196;
        int py = p / 14;
        int pos = (py + 1)*16 + (p - py*14) + 1;
        int cb = (c >> 3) ^ (pos & 3);            // XOR-swizzled 16B sub-block
        tile[pos][cb*8 + (c & 7)] = f2bf(r[j]);
      }
    }
  }
}

template<int CIN, int MODE>
__launch_bounds__(256, 2)
__global__ void k_conv3m(const float* __restrict__ in, const float* __restrict__ invn,
                         const unsigned short* __restrict__ wT, const float* __restrict__ bias,
                         float* __restrict__ out){
  constexpr int CPAD = (CIN + 31) & ~31;
  constexpr int T = CPAD / 32;
  const int b = blockIdx.x, z = blockIdx.y;
  const int o0 = blockIdx.z * 64;
  const int chBeg = (z*T)/2, chEnd = ((z+1)*T)/2;
  const int tid = threadIdx.x, wave = tid >> 6, lane = tid & 63;
  const int lr = lane & 15, lk = lane >> 4;
  const int wfM = wave >> 1, wfN = wave & 1;

  __shared__ unsigned short tile[2][296][40];
  __shared__ float sInv[200];

  for (int i = tid; i < 2*296*40; i += 256) (&tile[0][0][0])[i] = 0;
  if (MODE == 0) for (int i = tid; i < 196; i += 256) sInv[i] = invn[b*196 + i];
  __syncthreads();
  conv_stage<CIN,MODE>(tile[0], in, sInv, b, chBeg*32, tid);
  __syncthreads();

  f32x4 acc[2][8];
  #pragma unroll
  for (int i = 0; i < 2; ++i)
    #pragma unroll
    for (int j = 0; j < 8; ++j) acc[i][j] = f32x4{0,0,0,0};

  for (int ch = chBeg; ch < chEnd; ++ch){
    const int cur = (ch - chBeg) & 1;
    #pragma unroll
    for (int dy = 0; dy < 3; ++dy){
      #pragma unroll
      for (int dx = 0; dx < 3; ++dx){
        const int dlt = dy*16 + dx;
        short8v a[2];
        #pragma unroll
        for (int rf = 0; rf < 2; ++rf)
          a[rf] = *(const short8v*)(wT + ((size_t)((dy*3+dx)*128) + o0 + wfM*32 + rf*16 + lr)*CPAD
                                       + ch*32 + lk*8);
        #pragma unroll
        for (int cf = 0; cf < 8; ++cf){
          const int pos2 = wfN*128 + cf*16 + lr + dlt;
          short8v bf = *(short8v*)&tile[cur][pos2][(lk ^ (pos2 & 3))*8];
          #pragma unroll
          for (int rf = 0; rf < 2; ++rf)
            acc[rf][cf] = MFMA16(a[rf], bf, acc[rf][cf]);
        }
      }
      // hide next-chunk staging under dy=1,2 MFMA groups
      if (dy == 0 && ch + 1 < chEnd)
        conv_stage<CIN,MODE>(tile[cur^1], in, sInv, b, (ch+1)*32, tid);
    }
    __syncthreads();
  }

  // epilogue: C row = oc (lk*4+j), col = pos (lr)
  #pragma unroll
  for (int rf = 0; rf < 2; ++rf){
    #pragma unroll
    for (int j = 0; j < 4; ++j){
      const int oc = o0 + wfM*32 + rf*16 + lk*4 + j;
      const float bz = z ? 0.f : bias[oc];
      #pragma unroll
      for (int cf = 0; cf < 8; ++cf){
        const int pos = wfN*128 + cf*16 + lr;
        const int py = pos >> 4, px = pos & 15;
        if (py < 14 && px < 14)
          out[(size_t)z*NE + ((size_t)b*OC_ + oc)*P_ + py*14 + px] = acc[rf][cf][j] + bz;
      }
    }
  }
}

// ---------------- BN stats over 2 partial slabs -------------------------------
__global__ void k_bnstats(const float* __restrict__ t, float* __restrict__ stats){
  int o = blockIdx.x;
  int tid = threadIdx.x;
  float s = 0.f, s2 = 0.f;
  #pragma unroll 4
  for (int i = tid; i < B_*P_; i += 256){
    int b = i / P_, p = i - (i/P_)*P_;
    size_t off = ((size_t)b*OC_ + o)*P_ + p;
    float v = t[off] + t[off + NE];
    s += v; s2 += v*v;
  }
  __shared__ float r1[256], r2[256];
  r1[tid] = s; r2[tid] = s2; __syncthreads();
  for (int st = 128; st; st >>= 1){
    if (tid < st){ r1[tid] += r1[tid+st]; r2[tid] += r2[tid+st]; }
    __syncthreads();
  }
  if (tid == 0){
    float n = (float)(B_*P_);
    float m = r1[0] / n;
    float var = r2[0] / n - m*m;
    stats[o*2]   = m;
    stats[o*2+1] = rsqrtf(var + 1e-5f);
  }
}

// ---------------- BN apply + relu (+ optional residual add) -------------------
template<bool ADD>
__global__ void k_bnapply(const float* __restrict__ t, const float* __restrict__ stats,
                          const float* __restrict__ g, const float* __restrict__ bb,
                          const float* __restrict__ addsrc, float* __restrict__ out){
  int idx = blockIdx.x*256 + threadIdx.x;
  if (idx >= NE) return;
  int o = (idx / P_) % OC_;
  float m = stats[o*2], is = stats[o*2+1];
  float x = t[idx] + t[idx + NE];
  float v = g[o]*(x-m)*is + bb[o];
  v = fmaxf(v, 0.f);
  if (ADD) v += addsrc[idx];
  out[idx] = v;
}

// ---------------- 1x1 conv over [v(128) | coord(2)] + bias + relu -------------
__launch_bounds__(256)
__global__ void k_conv1x1(const float* __restrict__ vin, const float* __restrict__ w,
                          const float* __restrict__ bias, float* __restrict__ out){
  const int b  = blockIdx.x;
  const int o0 = blockIdx.y * 64;
  const int tid = threadIdx.x;
  const int olane = tid & 63, pg = tid >> 6;
  const int o = o0 + olane;

  __shared__ float sV[32][196];
  __shared__ float sW[64][33];

  float acc[49];
  #pragma unroll
  for (int p = 0; p < 49; ++p) acc[p] = 0.f;

  for (int ch = 0; ch < 128; ch += 32){
    __syncthreads();
    for (int i = tid; i < 32*196; i += 256){
      int c = i / 196, p = i - c*196;
      sV[c][p] = vin[((size_t)b*128 + ch + c)*P_ + p];
    }
    for (int i = tid; i < 64*32; i += 256){
      int ol = i >> 5, c = i & 31;
      sW[ol][c] = w[(size_t)(o0+ol)*130 + ch + c];
    }
    __syncthreads();
    for (int c = 0; c < 32; ++c){
      float wv = sW[olane][c];
      #pragma unroll
      for (int p = 0; p < 49; ++p) acc[p] += sV[c][pg*49 + p] * wv;
    }
  }
  float w0 = w[(size_t)o*130 + 128], w1 = w[(size_t)o*130 + 129], bz = bias[o];
  #pragma unroll
  for (int p = 0; p < 49; ++p){
    int pp = pg*49 + p;
    float v = acc[p] + w0*c0f(pp) + w1*c1f(pp) + bz;
    out[((size_t)b*128 + o)*P_ + pp] = fmaxf(v, 0.f);
  }
}

} // namespace

// ---------------------------------------------------------------------------
extern "C" void kernel_launch(void* const* d_in, const int* in_sizes, int n_in,
                              void* d_out, int out_size, void* d_ws, size_t ws_size,
                              hipStream_t stream){
  (void)in_sizes; (void)n_in; (void)out_size; (void)ws_size;
  const int*   que  = (const int*)  d_in[0];
  const float* img  = (const float*)d_in[1];
  const float* emb  = (const float*)d_in[2];
  const float* wihf = (const float*)d_in[3];
  const float* whhf = (const float*)d_in[4];
  const float* bihf = (const float*)d_in[5];
  const float* bhhf = (const float*)d_in[6];
  const float* wihb = (const float*)d_in[7];
  const float* whhb = (const float*)d_in[8];
  const float* bihb = (const float*)d_in[9];
  const float* bhhb = (const float*)d_in[10];
  const float* convw = (const float*)d_in[11];
  const float* convb = (const float*)d_in[12];
  const float* bng  = (const float*)d_in[13];
  const float* bnb  = (const float*)d_in[14];
  const float* r1c1w = (const float*)d_in[15];
  const float* r1c1b = (const float*)d_in[16];
  const float* r1c2w = (const float*)d_in[17];
  const float* r1c2b = (const float*)d_in[18];
  const float* r1bng = (const float*)d_in[19];
  const float* r1bnb = (const float*)d_in[20];
  const float* r2c1w = (const float*)d_in[21];
  const float* r2c1b = (const float*)d_in[22];
  const float* r2c2w = (const float*)d_in[23];
  const float* r2c2b = (const float*)d_in[24];
  const float* r2bng = (const float*)d_in[25];
  const float* r2bnb = (const float*)d_in[26];

  float* out  = (float*)d_out;
  float* enc  = out;                        // 128*2048
  float* Q    = out + 262144;               // 32*128*2048
  float* vout = out + 262144 + 8388608;     // 128*128*196

  // ------ workspace layout (f32 units) ----------------------------------------
  float* ws = (float*)d_ws;
  unsigned short* xbf  = (unsigned short*)ws;            // 32*128*384 bf16
  float* p1 = ws + 786432;
  unsigned short* wihc = (unsigned short*)p1;            // 2*4096*384 bf16
  float* p2 = p1 + 1572864;
  unsigned short* whhc = (unsigned short*)p2;            // 2*4096*1024 bf16
  float* p3 = p2 + 4194304;
  float* bias2 = p3;                                     // 2*4096
  float* p4 = p3 + 8192;
  unsigned short* hstate = (unsigned short*)p4;          // 2par*2dir*128*1024 bf16
  float* p5 = p4 + 262144;
  float* cstate = p5;                                    // 2*128*1024
  float* p6 = p5 + 262144;
  float* part = p6;                                      // 128*4*196
  float* invn = p6 + 100352;                             // 128*196
  float* bufA = invn + 25088;                            // NE
  float* bufB = bufA + NE;                               // NE
  float* convOut = bufB + NE;                            // 2*NE partial slabs
  float* p7 = convOut + 2*(size_t)NE;
  float* stats = p7;                                     // 256
  float* p8 = p7 + 256;
  unsigned short* wTc  = (unsigned short*)p8;            // 9*128*1056 bf16
  float* p9 = p8 + 608256;
  unsigned short* wTr1 = (unsigned short*)p9;            // 9*128*128 bf16
  float* p10 = p9 + 73728;
  unsigned short* wTr2 = (unsigned short*)p10;           // 9*128*128 bf16

  hipMemsetAsync(hstate, 0, (size_t)(262144 + 262144)*sizeof(float), stream);

  // ------ conversions ---------------------------------------------------------
  k_cvtpad<<<6144, 256, 0, stream>>>(wihf, wihc,                     4096, 300, KX);
  k_cvtpad<<<6144, 256, 0, stream>>>(wihb, wihc + (size_t)4096*KX,   4096, 300, KX);
  k_cvtpad<<<16384,256, 0, stream>>>(whhf, whhc,                     4096, 1024, 1024);
  k_cvtpad<<<16384,256, 0, stream>>>(whhb, whhc + (size_t)4096*1024, 4096, 1024, 1024);
  k_bias2<<<32, 256, 0, stream>>>(bihf, bhhf, bihb, bhhb, bias2);
  k_embed_bf<<<6144, 256, 0, stream>>>(que, emb, xbf);
  k_cvt_wT<<<(9*128*1056 + 255)/256, 256, 0, stream>>>(convw, wTc, 1026, 1056);
  k_cvt_wT<<<(9*128*128 + 255)/256, 256, 0, stream>>>(r1c2w, wTr1, 128, 128);
  k_cvt_wT<<<(9*128*128 + 255)/256, 256, 0, stream>>>(r2c2w, wTr2, 128, 128);

  // ------ bi-LSTM -------------------------------------------------------------
  for (int s = 0; s < 32; ++s){
    unsigned short* hin  = hstate + (size_t)(s & 1)*262144;
    unsigned short* hout = hstate + (size_t)((s & 1)^1)*262144;
    k_step5<<<dim3(64,4), 256, 0, stream>>>(xbf, wihc, whhc, bias2,
                                            hin, hout, cstate, Q, s);
  }
  k_qnorm<<<4096, 256, 0, stream>>>(Q, enc);

  // ------ image branch --------------------------------------------------------
  k_sqpart<<<dim3(128,4), 256, 0, stream>>>(img, part);
  k_invnorm<<<(25088+255)/256, 256, 0, stream>>>(part, invn);

  k_conv3m<1026,0><<<dim3(128,2,2), 256, 0, stream>>>(img, invn, wTc, convb, convOut);
  k_bnstats<<<128, 256, 0, stream>>>(convOut, stats);
  k_bnapply<false><<<(NE+255)/256, 256, 0, stream>>>(convOut, stats, bng, bnb, bufA, bufA);

  // res block 1: bufA(v) -> bufB(v1) -> convOut -> bufA(v2+v1)
  k_conv1x1<<<dim3(128,2), 256, 0, stream>>>(bufA, r1c1w, r1c1b, bufB);
  k_conv3m<128,1><<<dim3(128,2,2), 256, 0, stream>>>(bufB, invn, wTr1, r1c2b, convOut);
  k_bnstats<<<128, 256, 0, stream>>>(convOut, stats);
  k_bnapply<true><<<(NE+255)/256, 256, 0, stream>>>(convOut, stats, r1bng, r1bnb, bufB, bufA);

  // res block 2: bufA -> bufB(v1) -> convOut -> vout
  k_conv1x1<<<dim3(128,2), 256, 0, stream>>>(bufA, r2c1w, r2c1b, bufB);
  k_conv3m<128,1><<<dim3(128,2,2), 256, 0, stream>>>(bufB, invn, wTr2, r2c2b, convOut);
  k_bnstats<<<128, 256, 0, stream>>>(convOut, stats);
  k_bnapply<true><<<(NE+255)/256, 256, 0, stream>>>(convOut, stats, r2bng, r2bnb, bufB, vout);
}

// Round 7
// 1076.167 us; speedup vs baseline: 1.4242x; 1.4242x over previous
//
#include <hip/hip_runtime.h>
#include <hip/hip_bf16.h>
#include <math.h>

// ---------------------------------------------------------------------------
// R7: pre-transposed bf16 conv inputs. k_mkimgT: img -> imgT[b][196][1056]
//     (invnorm+coords+pad fused). k_conv3t: N-split rows (2) x K-split (2),
//     pure-16B staging, MFMA-bound. conv1x1 emits v1T bf16 for res convs.
//     LSTM k_step5 unchanged.
// ---------------------------------------------------------------------------

namespace {

constexpr int S_ = 32, B_ = 128, H_ = 1024, P_ = 196, OC_ = 128;
constexpr int NE = B_ * OC_ * P_;        // elems of a [B][128][196] slab
constexpr int KX = 384;                  // padded x-K (300 -> 384)

typedef __attribute__((ext_vector_type(8))) short short8v;
typedef __attribute__((ext_vector_type(4))) float f32x4;
#define MFMA16(a, b, c) __builtin_amdgcn_mfma_f32_16x16x32_bf16((a), (b), (c), 0, 0, 0)

__device__ __forceinline__ float sigm(float x){ return 1.0f/(1.0f + expf(-x)); }
__device__ __forceinline__ float c0f(int p){ return ((float)p/14.0f - 7.0f)/7.0f; }
__device__ __forceinline__ float c1f(int p){ return ((float)(p%14) - 7.0f)/7.0f; }
__device__ __forceinline__ unsigned short f2bf(float x){
  __hip_bfloat16 h = __float2bfloat16(x);
  return *reinterpret_cast<unsigned short*>(&h);
}

// ---------------- weight convert f32 -> bf16, K-padded -----------------------
__global__ void k_cvtpad(const float* __restrict__ src, unsigned short* __restrict__ dst,
                         int rows, int ks, int kd){
  int i = blockIdx.x*256 + threadIdx.x;
  if (i >= rows*kd) return;
  int k = i % kd, r = i / kd;
  dst[i] = (k < ks) ? f2bf(src[r*ks + k]) : (unsigned short)0;
}

// conv weights [oc][cin][3][3] f32 -> wT [s][oc][cpad] bf16
__global__ void k_cvt_wT(const float* __restrict__ w, unsigned short* __restrict__ wT,
                         int cin, int cpad){
  int i = blockIdx.x*256 + threadIdx.x;
  if (i >= 9*128*cpad) return;
  int c = i % cpad; int t = i / cpad; int oc = t % 128; int s = t / 128;
  wT[i] = (c < cin) ? f2bf(w[((size_t)oc*cin + c)*9 + s]) : (unsigned short)0;
}

__global__ void k_bias2(const float* __restrict__ bif, const float* __restrict__ bhf,
                        const float* __restrict__ bib, const float* __restrict__ bhb,
                        float* __restrict__ out){
  int i = blockIdx.x*256 + threadIdx.x;
  if (i >= 8192) return;
  out[i] = (i < 4096) ? (bif[i] + bhf[i]) : (bib[i-4096] + bhb[i-4096]);
}

// ---------------- embedding -> bf16 x[s][b][384] ------------------------------
__global__ void k_embed_bf(const int* __restrict__ que, const float* __restrict__ emb,
                           unsigned short* __restrict__ x){
  int idx = blockIdx.x*256 + threadIdx.x;
  if (idx >= S_*B_*KX) return;
  int e = idx % KX; int sb = idx / KX; int b = sb % B_; int s = sb / B_;
  float v = 0.0f;
  if (e < 300){
    int t = que[b*S_ + s];
    if (t != 0) v = emb[t*300 + e];
  }
  x[idx] = f2bf(v);
}

// ---------------- one LSTM step via MFMA (v5: barrier-free K-loop) ------------
__launch_bounds__(256, 1)
__global__ void k_step5(const unsigned short* __restrict__ xbf,
                        const unsigned short* __restrict__ wihc,
                        const unsigned short* __restrict__ whhc,
                        const float* __restrict__ bias2,
                        const unsigned short* __restrict__ hin,
                        unsigned short* __restrict__ hout,
                        float* __restrict__ cst, float* __restrict__ Q, int s){
  const int dir = blockIdx.x >> 5;
  const int u0  = (blockIdx.x & 31) * 32;
  const int m0g = blockIdx.y * 32;
  const int tid = threadIdx.x, wave = tid >> 6, lane = tid & 63;
  const int lr = lane & 15, lk = lane >> 4;
  const int xs = dir ? (S_-1-s) : s;

  __shared__ unsigned short tA[32][1416];   // [m][k], pad 8
  __shared__ float sG[32][132];

  // ---- stage A once: x rows (384) + h rows (1024), 22 indep loads/thread ----
  {
    const int r = tid >> 3, sg = tid & 7;
    const unsigned short* xr = xbf + ((size_t)xs*B_ + m0g + r)*KX + sg*48;
    #pragma unroll
    for (int q = 0; q < 6; ++q)
      *(short8v*)&tA[r][sg*48 + q*8] = *(const short8v*)(xr + q*8);
    const unsigned short* hr = hin + ((size_t)dir*B_ + m0g + r)*H_ + sg*128;
    #pragma unroll
    for (int q = 0; q < 16; ++q)
      *(short8v*)&tA[r][384 + sg*128 + q*8] = *(const short8v*)(hr + q*8);
  }
  __syncthreads();

  const int wr0 = wave*1024 + u0 + lr;
  const unsigned short* bx0 = wihc + (size_t)dir*4096*KX + (size_t)wr0*KX;
  const unsigned short* bx1 = bx0 + (size_t)16*KX;
  const unsigned short* bh0 = whhc + (size_t)dir*4096*H_ + (size_t)wr0*H_;
  const unsigned short* bh1 = bh0 + (size_t)16*H_;

  f32x4 acc00{0,0,0,0}, acc01{0,0,0,0}, acc10{0,0,0,0}, acc11{0,0,0,0};

  #pragma unroll
  for (int ch = 0; ch < 12; ++ch){
    const int ko = ch*32 + lk*8;
    short8v a0 = *(short8v*)&tA[lr][ko];
    short8v a1 = *(short8v*)&tA[16 + lr][ko];
    short8v b0 = *(const short8v*)(bx0 + ko);
    short8v b1 = *(const short8v*)(bx1 + ko);
    acc00 = MFMA16(a0, b0, acc00); acc01 = MFMA16(a0, b1, acc01);
    acc10 = MFMA16(a1, b0, acc10); acc11 = MFMA16(a1, b1, acc11);
  }
  #pragma unroll
  for (int ch = 0; ch < 32; ++ch){
    const int kb = ch*32 + lk*8;
    const int ka = 384 + kb;
    short8v a0 = *(short8v*)&tA[lr][ka];
    short8v a1 = *(short8v*)&tA[16 + lr][ka];
    short8v b0 = *(const short8v*)(bh0 + kb);
    short8v b1 = *(const short8v*)(bh1 + kb);
    acc00 = MFMA16(a0, b0, acc00); acc01 = MFMA16(a0, b1, acc01);
    acc10 = MFMA16(a1, b0, acc10); acc11 = MFMA16(a1, b1, acc11);
  }

  #pragma unroll
  for (int j = 0; j < 4; ++j){
    const int rr = lk*4 + j;
    sG[rr][wave*32 + lr]            = acc00[j];
    sG[rr][wave*32 + 16 + lr]       = acc01[j];
    sG[16 + rr][wave*32 + lr]       = acc10[j];
    sG[16 + rr][wave*32 + 16 + lr]  = acc11[j];
  }
  __syncthreads();

  const float* bb = bias2 + (size_t)dir*4096;
  float* cc = cst + (size_t)dir*B_*H_;
  unsigned short* ho = hout + (size_t)dir*B_*H_;
  #pragma unroll
  for (int t = 0; t < 4; ++t){
    const int idx = tid + t*256;
    const int m = idx >> 5, u = idx & 31;
    const int ug = u0 + u, mg = m0g + m;
    float gi = sG[m][u]      + bb[ug];
    float gf = sG[m][32+u]   + bb[1024+ug];
    float gg = sG[m][64+u]   + bb[2048+ug];
    float go = sG[m][96+u]   + bb[3072+ug];
    float cold = cc[mg*H_ + ug];
    float cn = sigm(gf)*cold + sigm(gi)*tanhf(gg);
    float hn = sigm(go)*tanhf(cn);
    cc[mg*H_ + ug] = cn;
    ho[mg*H_ + ug] = f2bf(hn);
    Q[((size_t)xs*B_ + mg)*2048 + dir*1024 + ug] = hn;
  }
}

// ---------------- qenc L2-normalize (in-place) + enc --------------------------
__global__ void k_qnorm(float* __restrict__ Q, float* __restrict__ enc){
  int sb = blockIdx.x;
  int s = sb >> 7, b = sb & 127;
  float* row = Q + (size_t)sb*2048;
  int tid = threadIdx.x;
  float v[8]; float ss = 0.f;
  #pragma unroll
  for (int i = 0; i < 8; ++i){ v[i] = row[tid*8+i]; ss += v[i]*v[i]; }
  __shared__ float red[256];
  red[tid] = ss; __syncthreads();
  for (int st = 128; st; st >>= 1){
    if (tid < st) red[tid] += red[tid+st];
    __syncthreads();
  }
  float inv = 1.0f / fmaxf(sqrtf(red[0]), 1e-12f);
  #pragma unroll
  for (int i = 0; i < 8; ++i){
    float q = v[i]*inv;
    row[tid*8+i] = q;
    if (s == S_-1) enc[(size_t)b*2048 + tid*8 + i] = q;
  }
}

// ---------------- per-pixel channel sumsq of img ------------------------------
__global__ void k_sqpart(const float* __restrict__ img, float* __restrict__ part){
  int b = blockIdx.x, cq = blockIdx.y;
  int t = threadIdx.x;
  if (t >= P_) return;
  const float* base = img + ((size_t)b*1024 + cq*256)*P_ + t;
  float s = 0.f;
  #pragma unroll 4
  for (int c = 0; c < 256; ++c){ float v = base[c*P_]; s += v*v; }
  part[((size_t)b*4 + cq)*P_ + t] = s;
}

__global__ void k_invnorm(const float* __restrict__ part, float* __restrict__ inv){
  int i = blockIdx.x*256 + threadIdx.x;
  if (i >= B_*P_) return;
  int b = i / P_, p = i % P_;
  float s = part[(b*4+0)*P_+p] + part[(b*4+1)*P_+p]
          + part[(b*4+2)*P_+p] + part[(b*4+3)*P_+p];
  inv[i] = 1.0f / fmaxf(sqrtf(s), 1e-12f);
}

// ---------------- img -> imgT[b][196][1056] bf16 (invnorm+coords+pad) ---------
__global__ void k_mkimgT(const float* __restrict__ img, const float* __restrict__ invn,
                         unsigned short* __restrict__ imgT){
  const int b = blockIdx.x, cg = blockIdx.y;
  const int tid = threadIdx.x;
  unsigned short* dstB = imgT + (size_t)b*196*1056;
  if (cg == 8){           // coord channels 1024,1025 + zero pad to 1055
    for (int i = tid; i < 196*32; i += 256){
      int p = i >> 5, cc = i & 31;
      float v = (cc == 0) ? c0f(p) : (cc == 1) ? c1f(p) : 0.f;
      dstB[(size_t)p*1056 + 1024 + cc] = f2bf(v);
    }
    return;
  }
  __shared__ unsigned short tt[196][136];
  __shared__ float sInv[200];
  for (int i = tid; i < 196; i += 256) sInv[i] = invn[b*196 + i];
  __syncthreads();
  const int c0 = cg*128;
  const float* srcB = img + ((size_t)b*1024 + c0)*196;
  for (int i = tid; i < 128*49; i += 256){
    int c = i / 49, p4 = i - (i/49)*49;
    float4 v = *(const float4*)(srcB + (size_t)c*196 + p4*4);
    int p = p4*4;
    tt[p+0][c] = f2bf(v.x * sInv[p+0]);
    tt[p+1][c] = f2bf(v.y * sInv[p+1]);
    tt[p+2][c] = f2bf(v.z * sInv[p+2]);
    tt[p+3][c] = f2bf(v.w * sInv[p+3]);
  }
  __syncthreads();
  for (int i = tid; i < 196*16; i += 256){
    int p = i >> 4, g = i & 15;
    *(short8v*)(dstB + (size_t)p*1056 + c0 + g*8) = *(short8v*)&tt[p][g*8];
  }
}

// ---------------- 3x3 conv via MFMA (v5: T-layout input, N-split rows) --------
// grid (128 b, 2 n, 2 z); block 256 (4 waves: wfM2 x wfN2).
// Block: M=128 oc (A=weights from L2), N=128 positions (8 image rows; n0 =
// out rows 0..7, n1 = 6..13 with epilogue-partition), K chunks of 32.
// Staging = pure 16B copies from srcT[b][196][CPAD].
template<int CPAD>
__device__ __forceinline__ void stage3t(unsigned short (*__restrict__ tile)[40],
                                        const unsigned short* __restrict__ src,
                                        int c0, int r0, int tid){
  for (int i = tid; i < 10*14*4; i += 256){
    int t = i / 56, rem = i - t*56, gx = rem >> 2, seg = rem & 3;
    int gy = r0 - 1 + t;
    if ((unsigned)gy < 14u){
      short8v v = *(const short8v*)(src + (size_t)(gy*14+gx)*CPAD + c0 + seg*8);
      *(short8v*)&tile[t*16 + gx + 1][seg*8] = v;
    }
  }
}

template<int CPAD>
__launch_bounds__(256, 2)
__global__ void k_conv3t(const unsigned short* __restrict__ srcT,
                         const unsigned short* __restrict__ wT,
                         const float* __restrict__ bias,
                         float* __restrict__ out){
  constexpr int T = CPAD / 32;
  const int b = blockIdx.x, n = blockIdx.y, z = blockIdx.z;
  const int r0 = n ? 6 : 0;
  const int chBeg = z ? T/2 : 0, chEnd = z ? T : T/2;
  const int tid = threadIdx.x, wave = tid >> 6, lane = tid & 63;
  const int lr = lane & 15, lk = lane >> 4;
  const int wfM = wave >> 1, wfN = wave & 1;
  const unsigned short* src = srcT + (size_t)b*196*CPAD;

  __shared__ unsigned short tile[2][164][40];

  for (int i = tid; i < 1640; i += 256)
    ((short8v*)&tile[0][0][0])[i] = short8v{0,0,0,0,0,0,0,0};
  __syncthreads();
  stage3t<CPAD>(tile[0], src, chBeg*32, r0, tid);
  __syncthreads();

  f32x4 acc[4][4];
  #pragma unroll
  for (int i = 0; i < 4; ++i)
    #pragma unroll
    for (int j = 0; j < 4; ++j) acc[i][j] = f32x4{0,0,0,0};

  for (int ch = chBeg; ch < chEnd; ++ch){
    const int cur = (ch - chBeg) & 1;
    #pragma unroll
    for (int dy = 0; dy < 3; ++dy){
      #pragma unroll
      for (int dx = 0; dx < 3; ++dx){
        const int dlt = dy*16 + dx;
        short8v a[4];
        #pragma unroll
        for (int rf = 0; rf < 4; ++rf)
          a[rf] = *(const short8v*)(wT + ((size_t)((dy*3+dx)*128) + wfM*64 + rf*16 + lr)*CPAD
                                       + ch*32 + lk*8);
        #pragma unroll
        for (int cf = 0; cf < 4; ++cf){
          short8v bf = *(short8v*)&tile[cur][wfN*64 + cf*16 + lr + dlt][lk*8];
          #pragma unroll
          for (int rf = 0; rf < 4; ++rf)
            acc[rf][cf] = MFMA16(a[rf], bf, acc[rf][cf]);
        }
      }
      if (dy == 0 && ch + 1 < chEnd)
        stage3t<CPAD>(tile[cur^1], src, (ch+1)*32, r0, tid);
    }
    __syncthreads();
  }

  // epilogue: C row = oc (lk*4+j), col = pos (lr); n-partitioned rows
  #pragma unroll
  for (int rf = 0; rf < 4; ++rf){
    #pragma unroll
    for (int j = 0; j < 4; ++j){
      const int oc = wfM*64 + rf*16 + lk*4 + j;
      const float bz = z ? 0.f : bias[oc];
      #pragma unroll
      for (int cf = 0; cf < 4; ++cf){
        const int pos = wfN*64 + cf*16 + lr;
        const int py = r0 + (pos >> 4), px = pos & 15;
        const bool rowok = n ? (py >= 8) : true;
        if (rowok && px < 14)
          out[(size_t)z*NE + ((size_t)b*OC_ + oc)*P_ + py*14 + px] = acc[rf][cf][j] + bz;
      }
    }
  }
}

// ---------------- BN stats over 2 partial slabs -------------------------------
__global__ void k_bnstats(const float* __restrict__ t, float* __restrict__ stats){
  int o = blockIdx.x;
  int tid = threadIdx.x;
  float s = 0.f, s2 = 0.f;
  #pragma unroll 4
  for (int i = tid; i < B_*P_; i += 256){
    int b = i / P_, p = i - (i/P_)*P_;
    size_t off = ((size_t)b*OC_ + o)*P_ + p;
    float v = t[off] + t[off + NE];
    s += v; s2 += v*v;
  }
  __shared__ float r1[256], r2[256];
  r1[tid] = s; r2[tid] = s2; __syncthreads();
  for (int st = 128; st; st >>= 1){
    if (tid < st){ r1[tid] += r1[tid+st]; r2[tid] += r2[tid+st]; }
    __syncthreads();
  }
  if (tid == 0){
    float n = (float)(B_*P_);
    float m = r1[0] / n;
    float var = r2[0] / n - m*m;
    stats[o*2]   = m;
    stats[o*2+1] = rsqrtf(var + 1e-5f);
  }
}

// ---------------- BN apply + relu (+ optional residual add) -------------------
template<bool ADD>
__global__ void k_bnapply(const float* __restrict__ t, const float* __restrict__ stats,
                          const float* __restrict__ g, const float* __restrict__ bb,
                          const float* __restrict__ addsrc, float* __restrict__ out){
  int idx = blockIdx.x*256 + threadIdx.x;
  if (idx >= NE) return;
  int o = (idx / P_) % OC_;
  float m = stats[o*2], is = stats[o*2+1];
  float x = t[idx] + t[idx + NE];
  float v = g[o]*(x-m)*is + bb[o];
  v = fmaxf(v, 0.f);
  if (ADD) v += addsrc[idx];
  out[idx] = v;
}

// ---------------- 1x1 conv + relu; writes f32 [b][c][p] AND bf16 [b][p][c] ----
__launch_bounds__(256)
__global__ void k_conv1x1(const float* __restrict__ vin, const float* __restrict__ w,
                          const float* __restrict__ bias, float* __restrict__ out,
                          unsigned short* __restrict__ outT){
  const int b  = blockIdx.x;
  const int o0 = blockIdx.y * 64;
  const int tid = threadIdx.x;
  const int olane = tid & 63, pg = tid >> 6;
  const int o = o0 + olane;

  __shared__ float sV[32][196];
  __shared__ float sW[64][33];

  float acc[49];
  #pragma unroll
  for (int p = 0; p < 49; ++p) acc[p] = 0.f;

  for (int ch = 0; ch < 128; ch += 32){
    __syncthreads();
    for (int i = tid; i < 32*196; i += 256){
      int c = i / 196, p = i - c*196;
      sV[c][p] = vin[((size_t)b*128 + ch + c)*P_ + p];
    }
    for (int i = tid; i < 64*32; i += 256){
      int ol = i >> 5, c = i & 31;
      sW[ol][c] = w[(size_t)(o0+ol)*130 + ch + c];
    }
    __syncthreads();
    for (int c = 0; c < 32; ++c){
      float wv = sW[olane][c];
      #pragma unroll
      for (int p = 0; p < 49; ++p) acc[p] += sV[c][pg*49 + p] * wv;
    }
  }
  float w0 = w[(size_t)o*130 + 128], w1 = w[(size_t)o*130 + 129], bz = bias[o];
  #pragma unroll
  for (int p = 0; p < 49; ++p){
    int pp = pg*49 + p;
    float v = acc[p] + w0*c0f(pp) + w1*c1f(pp) + bz;
    v = fmaxf(v, 0.f);
    out[((size_t)b*128 + o)*P_ + pp] = v;
    outT[((size_t)b*P_ + pp)*128 + o] = f2bf(v);
  }
}

} // namespace

// ---------------------------------------------------------------------------
extern "C" void kernel_launch(void* const* d_in, const int* in_sizes, int n_in,
                              void* d_out, int out_size, void* d_ws, size_t ws_size,
                              hipStream_t stream){
  (void)in_sizes; (void)n_in; (void)out_size; (void)ws_size;
  const int*   que  = (const int*)  d_in[0];
  const float* img  = (const float*)d_in[1];
  const float* emb  = (const float*)d_in[2];
  const float* wihf = (const float*)d_in[3];
  const float* whhf = (const float*)d_in[4];
  const float* bihf = (const float*)d_in[5];
  const float* bhhf = (const float*)d_in[6];
  const float* wihb = (const float*)d_in[7];
  const float* whhb = (const float*)d_in[8];
  const float* bihb = (const float*)d_in[9];
  const float* bhhb = (const float*)d_in[10];
  const float* convw = (const float*)d_in[11];
  const float* convb = (const float*)d_in[12];
  const float* bng  = (const float*)d_in[13];
  const float* bnb  = (const float*)d_in[14];
  const float* r1c1w = (const float*)d_in[15];
  const float* r1c1b = (const float*)d_in[16];
  const float* r1c2w = (const float*)d_in[17];
  const float* r1c2b = (const float*)d_in[18];
  const float* r1bng = (const float*)d_in[19];
  const float* r1bnb = (const float*)d_in[20];
  const float* r2c1w = (const float*)d_in[21];
  const float* r2c1b = (const float*)d_in[22];
  const float* r2c2w = (const float*)d_in[23];
  const float* r2c2b = (const float*)d_in[24];
  const float* r2bng = (const float*)d_in[25];
  const float* r2bnb = (const float*)d_in[26];

  float* out  = (float*)d_out;
  float* enc  = out;                        // 128*2048
  float* Q    = out + 262144;               // 32*128*2048
  float* vout = out + 262144 + 8388608;     // 128*128*196

  // ------ workspace layout (f32 units) ----------------------------------------
  float* ws = (float*)d_ws;
  unsigned short* xbf  = (unsigned short*)ws;            // 32*128*384 bf16
  float* p1 = ws + 786432;
  unsigned short* wihc = (unsigned short*)p1;            // 2*4096*384 bf16
  float* p2 = p1 + 1572864;
  unsigned short* whhc = (unsigned short*)p2;            // 2*4096*1024 bf16
  float* p3 = p2 + 4194304;
  float* bias2 = p3;                                     // 2*4096
  float* p4 = p3 + 8192;
  unsigned short* hstate = (unsigned short*)p4;          // 2par*2dir*128*1024 bf16
  float* p5 = p4 + 262144;
  float* cstate = p5;                                    // 2*128*1024
  float* p6 = p5 + 262144;
  float* part = p6;                                      // 128*4*196
  float* invn = p6 + 100352;                             // 128*196
  float* bufA = invn + 25088;                            // NE
  float* bufB = bufA + NE;                               // NE
  float* convOut = bufB + NE;                            // 2*NE partial slabs
  float* p7 = convOut + 2*(size_t)NE;
  float* stats = p7;                                     // 256
  float* p8 = p7 + 256;
  unsigned short* wTc  = (unsigned short*)p8;            // 9*128*1056 bf16
  float* p9 = p8 + 608256;
  unsigned short* wTr1 = (unsigned short*)p9;            // 9*128*128 bf16
  float* p10 = p9 + 73728;
  unsigned short* wTr2 = (unsigned short*)p10;           // 9*128*128 bf16
  float* p11 = p10 + 73728;
  unsigned short* imgT = (unsigned short*)p11;           // 128*196*1056 bf16
  float* p12 = p11 + 13246464;
  unsigned short* v1T  = (unsigned short*)p12;           // 128*196*128 bf16

  hipMemsetAsync(hstate, 0, (size_t)(262144 + 262144)*sizeof(float), stream);

  // ------ conversions ---------------------------------------------------------
  k_cvtpad<<<6144, 256, 0, stream>>>(wihf, wihc,                     4096, 300, KX);
  k_cvtpad<<<6144, 256, 0, stream>>>(wihb, wihc + (size_t)4096*KX,   4096, 300, KX);
  k_cvtpad<<<16384,256, 0, stream>>>(whhf, whhc,                     4096, 1024, 1024);
  k_cvtpad<<<16384,256, 0, stream>>>(whhb, whhc + (size_t)4096*1024, 4096, 1024, 1024);
  k_bias2<<<32, 256, 0, stream>>>(bihf, bhhf, bihb, bhhb, bias2);
  k_embed_bf<<<6144, 256, 0, stream>>>(que, emb, xbf);
  k_cvt_wT<<<(9*128*1056 + 255)/256, 256, 0, stream>>>(convw, wTc, 1026, 1056);
  k_cvt_wT<<<(9*128*128 + 255)/256, 256, 0, stream>>>(r1c2w, wTr1, 128, 128);
  k_cvt_wT<<<(9*128*128 + 255)/256, 256, 0, stream>>>(r2c2w, wTr2, 128, 128);

  // ------ bi-LSTM -------------------------------------------------------------
  for (int s = 0; s < 32; ++s){
    unsigned short* hin  = hstate + (size_t)(s & 1)*262144;
    unsigned short* hout = hstate + (size_t)((s & 1)^1)*262144;
    k_step5<<<dim3(64,4), 256, 0, stream>>>(xbf, wihc, whhc, bias2,
                                            hin, hout, cstate, Q, s);
  }
  k_qnorm<<<4096, 256, 0, stream>>>(Q, enc);

  // ------ image branch --------------------------------------------------------
  k_sqpart<<<dim3(128,4), 256, 0, stream>>>(img, part);
  k_invnorm<<<(25088+255)/256, 256, 0, stream>>>(part, invn);
  k_mkimgT<<<dim3(128,9), 256, 0, stream>>>(img, invn, imgT);

  k_conv3t<1056><<<dim3(128,2,2), 256, 0, stream>>>(imgT, wTc, convb, convOut);
  k_bnstats<<<128, 256, 0, stream>>>(convOut, stats);
  k_bnapply<false><<<(NE+255)/256, 256, 0, stream>>>(convOut, stats, bng, bnb, bufA, bufA);

  // res block 1: bufA(v) -> bufB/v1T(v1) -> convOut -> bufA(v2+v1)
  k_conv1x1<<<dim3(128,2), 256, 0, stream>>>(bufA, r1c1w, r1c1b, bufB, v1T);
  k_conv3t<128><<<dim3(128,2,2), 256, 0, stream>>>(v1T, wTr1, r1c2b, convOut);
  k_bnstats<<<128, 256, 0, stream>>>(convOut, stats);
  k_bnapply<true><<<(NE+255)/256, 256, 0, stream>>>(convOut, stats, r1bng, r1bnb, bufB, bufA);

  // res block 2: bufA -> bufB/v1T(v1) -> convOut -> vout
  k_conv1x1<<<dim3(128,2), 256, 0, stream>>>(bufA, r2c1w, r2c1b, bufB, v1T);
  k_conv3t<128><<<dim3(128,2,2), 256, 0, stream>>>(v1T, wTr2, r2c2b, convOut);
  k_bnstats<<<128, 256, 0, stream>>>(convOut, stats);
  k_bnapply<true><<<(NE+255)/256, 256, 0, stream>>>(convOut, stats, r2bng, r2bnb, bufB, vout);
}